// Round 1
// baseline (1240.115 us; speedup 1.0000x reference)
//
#include <hip/hip_runtime.h>

#define D_ 1024
#define S_ 2048
#define B_ 32
#define BM 128
#define BN 128
#define BK 32
#define NKT 64  // K tiles: 32 from W/k + 32 from U/q

typedef unsigned short ushort_t;
typedef __attribute__((ext_vector_type(8))) short short8v;   // 8 bf16 = 4 VGPR
typedef __attribute__((ext_vector_type(16))) float f32x16;   // MFMA 32x32 acc
typedef __attribute__((ext_vector_type(4))) unsigned int u32x4;

// ---------------------------------------------------------------------------
// prep: split W,U (f32) into bf16 hi/lo, stored in swizzled tiled layout.
// Tile (mt,kt) = rows d in [mt*128, +128) x cols e in [kt*32, +32), 4096 bf16.
// In-tile f16 offset for (m, e): m*32 + ((kc ^ (m&3))<<3) + (e&7),  kc=(e>>3)&3
// -> a linear 8KB copy into LDS reproduces the XOR-swizzled image the MFMA
//    fragment ds_read_b128s expect (bank-conflict-free reads).
// ---------------------------------------------------------------------------
__global__ void prep_kernel(const float* __restrict__ W, const float* __restrict__ U,
                            ushort_t* __restrict__ whi, ushort_t* __restrict__ wlo,
                            ushort_t* __restrict__ uhi, ushort_t* __restrict__ ulo) {
  int t = blockIdx.x * blockDim.x + threadIdx.x;  // [0, 131072) = 1024 d x 128 e-chunks
  int e8 = t & 127;
  int d  = t >> 7;
  const float* src = blockIdx.y ? U : W;
  ushort_t* dhi = blockIdx.y ? uhi : whi;
  ushort_t* dlo = blockIdx.y ? ulo : wlo;
  int e  = e8 << 3;
  int mt = d >> 7, m = d & 127;
  int kt = e >> 5, kc = (e >> 3) & 3;
  size_t off = (size_t)(mt * 32 + kt) * 4096 + (size_t)m * 32 + (size_t)((kc ^ (m & 3)) << 3);
  const float* p = src + (size_t)d * D_ + e;
  ushort_t hi[8], lo[8];
#pragma unroll
  for (int j = 0; j < 8; ++j) {
    float x = p[j];
    unsigned u = __float_as_uint(x);
    unsigned hb = u & 0xFFFF0000u;          // hi = truncate-to-bf16 (exact residual below)
    float lf = x - __uint_as_float(hb);     // exact in f32
    hi[j] = (ushort_t)(hb >> 16);
    lo[j] = (ushort_t)((__float_as_uint(lf) + 0x8000u) >> 16);  // round lo to bf16
  }
  u32x4 hv, lv;
#pragma unroll
  for (int w = 0; w < 4; ++w) {
    hv[w] = (unsigned)hi[2 * w] | ((unsigned)hi[2 * w + 1] << 16);
    lv[w] = (unsigned)lo[2 * w] | ((unsigned)lo[2 * w + 1] << 16);
  }
  *(u32x4*)(dhi + off) = hv;
  *(u32x4*)(dlo + off) = lv;
}

// ---------------------------------------------------------------------------
// gemm: per (b, s-tile, d-tile): fac = [W|U] @ [k;q] via split-bf16 3-pass
// MFMA (hi*hi + hi*lo + lo*hi, shared f32 accumulator), then
// partial[dblk][b][s] = sum_d v[d] * tanh(fac[d][s]) over the 128-row d-tile.
// ---------------------------------------------------------------------------
__global__ void __launch_bounds__(256, 3)
gemm_kernel(const float* __restrict__ kten, const float* __restrict__ qten,
            const float* __restrict__ v,
            const ushort_t* __restrict__ whi, const ushort_t* __restrict__ wlo,
            const ushort_t* __restrict__ uhi, const ushort_t* __restrict__ ulo,
            float* __restrict__ partials) {
  __shared__ __align__(16) ushort_t Ah[BM * BK];
  __shared__ __align__(16) ushort_t Al[BM * BK];
  __shared__ __align__(16) ushort_t Bh[BN * BK];
  __shared__ __align__(16) ushort_t Bl[BN * BK];
  __shared__ float vbuf[BM];
  __shared__ float red[2][BN];

  const int tid  = threadIdx.x;
  const int lane = tid & 63;
  const int wid  = tid >> 6;
  const int wr   = wid >> 1, wc = wid & 1;

  // Block decode: bid = [ghi:6][dblk:3][glow:3]. The 8 d-sibling blocks of a
  // (b, s-tile) group share bid&7 -> same XCD under round-robin dispatch, and
  // are 8 slots apart -> co-scheduled -> k/q tiles served from L2.
  int bid  = blockIdx.x;
  int g    = ((bid >> 6) << 3) | (bid & 7);  // [0,512)
  int dblk = (bid >> 3) & 7;
  int st   = g & 15;
  int b    = g >> 4;
  int s0   = st * BN;

  if (tid < BM) vbuf[tid] = v[(size_t)b * D_ + dblk * BM + tid];

  f32x16 acc[2][2];
#pragma unroll
  for (int i = 0; i < 2; ++i)
#pragma unroll
    for (int j = 0; j < 2; ++j)
#pragma unroll
      for (int r = 0; r < 16; ++r) acc[i][j][r] = 0.0f;

  const int nB = tid & 127;  // B-stage column within s-tile
  const int kq = tid >> 7;   // 0/1: which 16 k-rows this thread loads

  for (int kt = 0; kt < NKT; ++kt) {
    const int half = kt >> 5;  // 0: W with k, 1: U with q
    const int ktt  = kt & 31;
    const ushort_t* ah = (half ? uhi : whi) + (size_t)(dblk * 32 + ktt) * 4096;
    const ushort_t* al = (half ? ulo : wlo) + (size_t)(dblk * 32 + ktt) * 4096;
    const float* xb = (half ? qten : kten) + (size_t)b * (D_ * S_) + (size_t)(ktt * 32) * S_ + s0;

    __syncthreads();  // previous compute done reading LDS

    // ---- stage A: linear copy of pre-swizzled 8KB tiles (hi, lo) ----
    {
      const u32x4* sh = (const u32x4*)ah;
      const u32x4* sl = (const u32x4*)al;
      u32x4* dh = (u32x4*)Ah;
      u32x4* dl = (u32x4*)Al;
      dh[tid]       = sh[tid];
      dh[tid + 256] = sh[tid + 256];
      dl[tid]       = sl[tid];
      dl[tid + 256] = sl[tid + 256];
    }

    // ---- stage B: f32 loads (coalesced across lanes), split hi/lo, swizzled
    //      transpose write into [n][k] layout ----
    {
      float xv[16];
      const float* col = xb + nB + (size_t)(kq * 16) * S_;
#pragma unroll
      for (int j = 0; j < 16; ++j) xv[j] = col[(size_t)j * S_];
      ushort_t hi[16], lo[16];
#pragma unroll
      for (int j = 0; j < 16; ++j) {
        unsigned u = __float_as_uint(xv[j]);
        unsigned hb = u & 0xFFFF0000u;
        float lf = xv[j] - __uint_as_float(hb);
        hi[j] = (ushort_t)(hb >> 16);
        lo[j] = (ushort_t)((__float_as_uint(lf) + 0x8000u) >> 16);
      }
#pragma unroll
      for (int jj = 0; jj < 2; ++jj) {
        int kc  = kq * 2 + jj;
        int off = nB * 32 + ((kc ^ (nB & 3)) << 3);
        u32x4 hv, lv;
#pragma unroll
        for (int w = 0; w < 4; ++w) {
          hv[w] = (unsigned)hi[jj * 8 + 2 * w] | ((unsigned)hi[jj * 8 + 2 * w + 1] << 16);
          lv[w] = (unsigned)lo[jj * 8 + 2 * w] | ((unsigned)lo[jj * 8 + 2 * w + 1] << 16);
        }
        *(u32x4*)&Bh[off] = hv;
        *(u32x4*)&Bl[off] = lv;
      }
    }

    __syncthreads();  // staged tiles visible

    // ---- compute: 2 k-steps x 2x2 frags x 3 split passes = 24 MFMA ----
#pragma unroll
    for (int ks = 0; ks < 2; ++ks) {
      const int c  = ks * 2 + (lane >> 5);
      const int r0 = wr * 64 + (lane & 31);
      short8v ahf[2], alf[2], bhf[2], blf[2];
#pragma unroll
      for (int fm = 0; fm < 2; ++fm) {
        int r   = r0 + fm * 32;
        int off = r * 32 + ((c ^ (r & 3)) << 3);
        ahf[fm] = *(const short8v*)&Ah[off];
        alf[fm] = *(const short8v*)&Al[off];
      }
      const int n0 = wc * 64 + (lane & 31);
#pragma unroll
      for (int fn = 0; fn < 2; ++fn) {
        int nn  = n0 + fn * 32;
        int off = nn * 32 + ((c ^ (nn & 3)) << 3);
        bhf[fn] = *(const short8v*)&Bh[off];
        blf[fn] = *(const short8v*)&Bl[off];
      }
#pragma unroll
      for (int fm = 0; fm < 2; ++fm)
#pragma unroll
        for (int fn = 0; fn < 2; ++fn) {
          acc[fm][fn] = __builtin_amdgcn_mfma_f32_32x32x16_bf16(ahf[fm], bhf[fn], acc[fm][fn], 0, 0, 0);
          acc[fm][fn] = __builtin_amdgcn_mfma_f32_32x32x16_bf16(ahf[fm], blf[fn], acc[fm][fn], 0, 0, 0);
          acc[fm][fn] = __builtin_amdgcn_mfma_f32_32x32x16_bf16(alf[fm], bhf[fn], acc[fm][fn], 0, 0, 0);
          // lo*lo dropped: ~2^-18 relative, negligible
        }
    }
  }

  // ---- epilogue: tanh, weight by v[d], reduce columns over the 128 d-rows ----
  float psum[2] = {0.f, 0.f};
#pragma unroll
  for (int fm = 0; fm < 2; ++fm)
#pragma unroll
    for (int fn = 0; fn < 2; ++fn)
#pragma unroll
      for (int r = 0; r < 16; ++r) {
        // C/D layout (verified m74/m101): col = lane&31, row = (r&3)+8*(r>>2)+4*(lane>>5)
        int row = wr * 64 + fm * 32 + (r & 3) + 8 * (r >> 2) + 4 * (lane >> 5);
        float x  = acc[fm][fn][r];
        float th = 1.0f - 2.0f / (__expf(2.0f * x) + 1.0f);  // tanh(x)
        psum[fn] += vbuf[row] * th;
      }
#pragma unroll
  for (int fn = 0; fn < 2; ++fn) psum[fn] += __shfl_xor(psum[fn], 32);
  if (lane < 32) {
    red[wr][wc * 64 + lane]      = psum[0];
    red[wr][wc * 64 + 32 + lane] = psum[1];
  }
  __syncthreads();
  if (tid < BN) {
    float val = red[0][tid] + red[1][tid];
    partials[(size_t)(dblk * B_ + b) * S_ + s0 + tid] = val;
  }
}

// ---------------------------------------------------------------------------
// softmax over S per batch; sums the 8 d-block partials first. Deterministic.
// ---------------------------------------------------------------------------
__global__ void softmax_kernel(const float* __restrict__ partials, float* __restrict__ out) {
  __shared__ float logit[S_];
  __shared__ float wred[2][4];
  int b = blockIdx.x, tid = threadIdx.x;
  int lane = tid & 63, wid = tid >> 6;
  float lmax = -1e30f;
  for (int i = tid; i < S_; i += 256) {
    float acc = 0.f;
#pragma unroll
    for (int d = 0; d < 8; ++d) acc += partials[(size_t)(d * B_ + b) * S_ + i];
    logit[i] = acc;
    lmax = fmaxf(lmax, acc);
  }
#pragma unroll
  for (int o = 32; o; o >>= 1) lmax = fmaxf(lmax, __shfl_xor(lmax, o));
  if (lane == 0) wred[0][wid] = lmax;
  __syncthreads();
  float m = fmaxf(fmaxf(wred[0][0], wred[0][1]), fmaxf(wred[0][2], wred[0][3]));
  float lsum = 0.f;
  for (int i = tid; i < S_; i += 256) {
    float ex = __expf(logit[i] - m);
    logit[i] = ex;
    lsum += ex;
  }
#pragma unroll
  for (int o = 32; o; o >>= 1) lsum += __shfl_xor(lsum, o);
  if (lane == 0) wred[1][wid] = lsum;
  __syncthreads();
  float tot = wred[1][0] + wred[1][1] + wred[1][2] + wred[1][3];
  float inv = 1.0f / tot;
  for (int i = tid; i < S_; i += 256) out[(size_t)b * S_ + i] = logit[i] * inv;
}

extern "C" void kernel_launch(void* const* d_in, const int* in_sizes, int n_in,
                              void* d_out, int out_size, void* d_ws, size_t ws_size,
                              hipStream_t stream) {
  const float* q = (const float*)d_in[0];
  const float* k = (const float*)d_in[1];
  const float* v = (const float*)d_in[2];
  const float* W = (const float*)d_in[3];
  const float* U = (const float*)d_in[4];

  // ws layout: 4x bf16[1024*1024] (8 MB) + partials f32[8][32][2048] (2 MB)
  ushort_t* whi = (ushort_t*)d_ws;
  ushort_t* wlo = whi + (size_t)D_ * D_;
  ushort_t* uhi = wlo + (size_t)D_ * D_;
  ushort_t* ulo = uhi + (size_t)D_ * D_;
  float* partials = (float*)(ulo + (size_t)D_ * D_);

  prep_kernel<<<dim3(512, 2), 256, 0, stream>>>(W, U, whi, wlo, uhi, ulo);
  gemm_kernel<<<dim3(4096), 256, 0, stream>>>(k, q, v, whi, wlo, uhi, ulo, partials);
  softmax_kernel<<<dim3(B_), 256, 0, stream>>>(partials, (float*)d_out);
}

// Round 2
// 847.969 us; speedup vs baseline: 1.4625x; 1.4625x over previous
//
#include <hip/hip_runtime.h>

#define D_ 1024
#define S_ 2048
#define B_ 32
#define BM 128
#define BN 128
#define BK 32
#define NKT 64  // K tiles: 32 from W/k + 32 from U/q

typedef unsigned short ushort_t;
typedef __attribute__((ext_vector_type(8))) short short8v;   // 8 bf16 = 4 VGPR
typedef __attribute__((ext_vector_type(16))) float f32x16;   // MFMA 32x32 acc
typedef __attribute__((ext_vector_type(4))) unsigned int u32x4;

// async global->LDS, 16B per lane. LDS dest is wave-uniform base + lane*16;
// our per-lane pointers are linear in lane, so this matches exactly.
__device__ __forceinline__ void async_ld16(const ushort_t* g, ushort_t* l) {
  __builtin_amdgcn_global_load_lds(
      (const __attribute__((address_space(1))) void*)g,
      (__attribute__((address_space(3))) void*)l, 16, 0, 0);
}

// ---------------------------------------------------------------------------
// prep: split W,U (f32) into bf16 hi/lo, stored in FRAGMENT ORDER per
// 128x32 tile: granule(m, chunk) = ((wr*2+ks)*2+fm)*64 + lhi*32 + l31
//   where m = wr*64+fm*32+l31 (row), chunk = ks*2+lhi (8-elem k-group).
// => gemm's A-stage is a linear 8KB copy (global_load_lds) and every MFMA
//    fragment ds_read_b128 is 64 lanes x 16B contiguous: zero bank conflicts.
// Writes here are fully linear/coalesced; reads scattered (one-time cost).
// ---------------------------------------------------------------------------
__global__ void prep_kernel(const float* __restrict__ W, const float* __restrict__ U,
                            ushort_t* __restrict__ whi, ushort_t* __restrict__ wlo,
                            ushort_t* __restrict__ uhi, ushort_t* __restrict__ ulo) {
  int t = blockIdx.x * blockDim.x + threadIdx.x;  // [0, 131072) granules
  const float* src = blockIdx.y ? U : W;
  ushort_t* dhi = blockIdx.y ? uhi : whi;
  ushort_t* dlo = blockIdx.y ? ulo : wlo;

  int tile = t >> 9;        // [0,256) = mt*32 + kt
  int g    = t & 511;       // granule within tile
  int top  = g >> 6, lane = g & 63;
  int wr = top >> 2, ks = (top >> 1) & 1, fm = top & 1;
  int l31 = lane & 31, lhi = lane >> 5;
  int m     = wr * 64 + fm * 32 + l31;
  int chunk = ks * 2 + lhi;
  int mt = tile >> 5, kt = tile & 31;
  int d = mt * 128 + m;
  int e = kt * 32 + chunk * 8;

  const float* p = src + (size_t)d * D_ + e;
  ushort_t hi[8], lo[8];
#pragma unroll
  for (int j = 0; j < 8; ++j) {
    float x = p[j];
    unsigned u = __float_as_uint(x);
    unsigned hb = u & 0xFFFF0000u;          // hi = truncate-to-bf16 (exact residual)
    float lf = x - __uint_as_float(hb);     // exact in f32
    hi[j] = (ushort_t)(hb >> 16);
    lo[j] = (ushort_t)((__float_as_uint(lf) + 0x8000u) >> 16);  // round lo
  }
  u32x4 hv, lv;
#pragma unroll
  for (int w = 0; w < 4; ++w) {
    hv[w] = (unsigned)hi[2 * w] | ((unsigned)hi[2 * w + 1] << 16);
    lv[w] = (unsigned)lo[2 * w] | ((unsigned)lo[2 * w + 1] << 16);
  }
  *(u32x4*)(dhi + (size_t)t * 8) = hv;   // linear, coalesced
  *(u32x4*)(dlo + (size_t)t * 8) = lv;
}

// ---------------------------------------------------------------------------
// gemm: per (b, s-tile, d-tile): fac = [W|U] @ [k;q] via split-bf16 3-pass
// MFMA (hi*hi + hi*lo + lo*hi, shared f32 accumulator), then
// partial[dblk][b][s] = sum_d v[d] * tanh(fac[d][s]) over the 128-row d-tile.
// All LDS traffic is fragment-order linear: zero bank conflicts by design.
// ---------------------------------------------------------------------------
__global__ void __launch_bounds__(256, 4)
gemm_kernel(const float* __restrict__ kten, const float* __restrict__ qten,
            const float* __restrict__ v,
            const ushort_t* __restrict__ whi, const ushort_t* __restrict__ wlo,
            const ushort_t* __restrict__ uhi, const ushort_t* __restrict__ ulo,
            float* __restrict__ partials) {
  __shared__ __align__(16) ushort_t Ah[BM * BK];
  __shared__ __align__(16) ushort_t Al[BM * BK];
  __shared__ __align__(16) ushort_t Bh[BN * BK];
  __shared__ __align__(16) ushort_t Bl[BN * BK];
  __shared__ float vbuf[BM];
  __shared__ float red[2][BN];

  const int tid  = threadIdx.x;
  const int lane = tid & 63;
  const int wid  = tid >> 6;
  const int wr   = wid >> 1, wc = wid & 1;

  // Block decode: the 8 d-sibling blocks of a (b, s-tile) group share bid&7
  // -> same XCD under round-robin dispatch -> k/q tiles served from L2.
  int bid  = blockIdx.x;
  int g    = ((bid >> 6) << 3) | (bid & 7);  // [0,512)
  int dblk = (bid >> 3) & 7;
  int st   = g & 15;
  int b    = g >> 4;
  int s0   = st * BN;

  if (tid < BM) vbuf[tid] = v[(size_t)b * D_ + dblk * BM + tid];

  f32x16 acc[2][2];
#pragma unroll
  for (int i = 0; i < 2; ++i)
#pragma unroll
    for (int j = 0; j < 2; ++j)
#pragma unroll
      for (int r = 0; r < 16; ++r) acc[i][j][r] = 0.0f;

  const int nB = tid & 127;  // B-stage column within s-tile
  const int kq = tid >> 7;   // 0/1: which 16 k-rows this thread loads

  for (int kt = 0; kt < NKT; ++kt) {
    const int half = kt >> 5;  // 0: W with k, 1: U with q
    const int ktt  = kt & 31;
    const size_t toff = (size_t)(dblk * 32 + ktt) * 4096;
    const ushort_t* ah = (half ? uhi : whi) + toff;
    const ushort_t* al = (half ? ulo : wlo) + toff;
    const float* xb = (half ? qten : kten) + (size_t)b * (D_ * S_) + (size_t)(ktt * 32) * S_ + s0;

    __syncthreads();  // previous compute done reading LDS

    // ---- stage A: async linear copy of fragment-ordered 8KB tiles ----
    async_ld16(ah + (size_t)tid * 8,         Ah + (size_t)tid * 8);
    async_ld16(ah + (size_t)(tid + 256) * 8, Ah + (size_t)(tid + 256) * 8);
    async_ld16(al + (size_t)tid * 8,         Al + (size_t)tid * 8);
    async_ld16(al + (size_t)(tid + 256) * 8, Al + (size_t)(tid + 256) * 8);

    // ---- stage B: f32 loads (coalesced across lanes), split hi/lo, write in
    //      fragment order: per wave two contiguous 32-granule runs, no conflicts
    {
      float xv[16];
      const float* col = xb + nB + (size_t)(kq * 16) * S_;
#pragma unroll
      for (int j = 0; j < 16; ++j) xv[j] = col[(size_t)j * S_];
      ushort_t hi[16], lo[16];
#pragma unroll
      for (int j = 0; j < 16; ++j) {
        unsigned u = __float_as_uint(xv[j]);
        unsigned hb = u & 0xFFFF0000u;
        float lf = xv[j] - __uint_as_float(hb);
        hi[j] = (ushort_t)(hb >> 16);
        lo[j] = (ushort_t)((__float_as_uint(lf) + 0x8000u) >> 16);
      }
#pragma unroll
      for (int jj = 0; jj < 2; ++jj) {
        // chunk kc = kq*2+jj  ->  granule = ((wc_n*2+kq)*2+fn_n)*64 + jj*32 + l31
        int gnl = ((((nB >> 6) * 2 + kq) * 2 + ((nB >> 5) & 1)) << 6) + (jj << 5) + (nB & 31);
        u32x4 hv, lv;
#pragma unroll
        for (int w = 0; w < 4; ++w) {
          hv[w] = (unsigned)hi[jj * 8 + 2 * w] | ((unsigned)hi[jj * 8 + 2 * w + 1] << 16);
          lv[w] = (unsigned)lo[jj * 8 + 2 * w] | ((unsigned)lo[jj * 8 + 2 * w + 1] << 16);
        }
        *(u32x4*)&Bh[(size_t)gnl * 8] = hv;
        *(u32x4*)&Bl[(size_t)gnl * 8] = lv;
      }
    }

    __syncthreads();  // staged tiles visible (sync waits vmcnt too)

    // ---- compute: 2 k-steps x 2x2 frags x 3 split passes = 24 MFMA ----
#pragma unroll
    for (int ks = 0; ks < 2; ++ks) {
      short8v ahf[2], alf[2], bhf[2], blf[2];
#pragma unroll
      for (int fm = 0; fm < 2; ++fm) {
        int gA = (((wr * 2 + ks) * 2 + fm) << 6) + lane;  // contiguous per wave
        ahf[fm] = *(const short8v*)&Ah[(size_t)gA * 8];
        alf[fm] = *(const short8v*)&Al[(size_t)gA * 8];
      }
#pragma unroll
      for (int fn = 0; fn < 2; ++fn) {
        int gB = (((wc * 2 + ks) * 2 + fn) << 6) + lane;
        bhf[fn] = *(const short8v*)&Bh[(size_t)gB * 8];
        blf[fn] = *(const short8v*)&Bl[(size_t)gB * 8];
      }
#pragma unroll
      for (int fm = 0; fm < 2; ++fm)
#pragma unroll
        for (int fn = 0; fn < 2; ++fn) {
          acc[fm][fn] = __builtin_amdgcn_mfma_f32_32x32x16_bf16(ahf[fm], bhf[fn], acc[fm][fn], 0, 0, 0);
          acc[fm][fn] = __builtin_amdgcn_mfma_f32_32x32x16_bf16(ahf[fm], blf[fn], acc[fm][fn], 0, 0, 0);
          acc[fm][fn] = __builtin_amdgcn_mfma_f32_32x32x16_bf16(alf[fm], bhf[fn], acc[fm][fn], 0, 0, 0);
          // lo*lo dropped: ~2^-18 relative, negligible
        }
    }
  }

  // ---- epilogue: tanh, weight by v[d], reduce columns over the 128 d-rows ----
  float psum[2] = {0.f, 0.f};
#pragma unroll
  for (int fm = 0; fm < 2; ++fm)
#pragma unroll
    for (int fn = 0; fn < 2; ++fn)
#pragma unroll
      for (int r = 0; r < 16; ++r) {
        // C/D layout: col = lane&31, row = (r&3)+8*(r>>2)+4*(lane>>5)
        int row = wr * 64 + fm * 32 + (r & 3) + 8 * (r >> 2) + 4 * (lane >> 5);
        float x  = acc[fm][fn][r];
        float th = 1.0f - 2.0f / (__expf(2.0f * x) + 1.0f);  // tanh(x)
        psum[fn] += vbuf[row] * th;
      }
#pragma unroll
  for (int fn = 0; fn < 2; ++fn) psum[fn] += __shfl_xor(psum[fn], 32);
  if (lane < 32) {
    red[wr][wc * 64 + lane]      = psum[0];
    red[wr][wc * 64 + 32 + lane] = psum[1];
  }
  __syncthreads();
  if (tid < BN) {
    float val = red[0][tid] + red[1][tid];
    partials[(size_t)(dblk * B_ + b) * S_ + s0 + tid] = val;
  }
}

// ---------------------------------------------------------------------------
// softmax over S per batch; sums the 8 d-block partials first. Deterministic.
// ---------------------------------------------------------------------------
__global__ void softmax_kernel(const float* __restrict__ partials, float* __restrict__ out) {
  __shared__ float logit[S_];
  __shared__ float wred[2][4];
  int b = blockIdx.x, tid = threadIdx.x;
  int lane = tid & 63, wid = tid >> 6;
  float lmax = -1e30f;
  for (int i = tid; i < S_; i += 256) {
    float acc = 0.f;
#pragma unroll
    for (int d = 0; d < 8; ++d) acc += partials[(size_t)(d * B_ + b) * S_ + i];
    logit[i] = acc;
    lmax = fmaxf(lmax, acc);
  }
#pragma unroll
  for (int o = 32; o; o >>= 1) lmax = fmaxf(lmax, __shfl_xor(lmax, o));
  if (lane == 0) wred[0][wid] = lmax;
  __syncthreads();
  float m = fmaxf(fmaxf(wred[0][0], wred[0][1]), fmaxf(wred[0][2], wred[0][3]));
  float lsum = 0.f;
  for (int i = tid; i < S_; i += 256) {
    float ex = __expf(logit[i] - m);
    logit[i] = ex;
    lsum += ex;
  }
#pragma unroll
  for (int o = 32; o; o >>= 1) lsum += __shfl_xor(lsum, o);
  if (lane == 0) wred[1][wid] = lsum;
  __syncthreads();
  float tot = wred[1][0] + wred[1][1] + wred[1][2] + wred[1][3];
  float inv = 1.0f / tot;
  for (int i = tid; i < S_; i += 256) out[(size_t)b * S_ + i] = logit[i] * inv;
}

extern "C" void kernel_launch(void* const* d_in, const int* in_sizes, int n_in,
                              void* d_out, int out_size, void* d_ws, size_t ws_size,
                              hipStream_t stream) {
  const float* q = (const float*)d_in[0];
  const float* k = (const float*)d_in[1];
  const float* v = (const float*)d_in[2];
  const float* W = (const float*)d_in[3];
  const float* U = (const float*)d_in[4];

  // ws layout: 4x bf16[1024*1024] (8 MB) + partials f32[8][32][2048] (2 MB)
  ushort_t* whi = (ushort_t*)d_ws;
  ushort_t* wlo = whi + (size_t)D_ * D_;
  ushort_t* uhi = wlo + (size_t)D_ * D_;
  ushort_t* ulo = uhi + (size_t)D_ * D_;
  float* partials = (float*)(ulo + (size_t)D_ * D_);

  prep_kernel<<<dim3(512, 2), 256, 0, stream>>>(W, U, whi, wlo, uhi, ulo);
  gemm_kernel<<<dim3(4096), 256, 0, stream>>>(k, q, v, whi, wlo, uhi, ulo, partials);
  softmax_kernel<<<dim3(B_), 256, 0, stream>>>(partials, (float*)d_out);
}